// Round 2
// baseline (231.571 us; speedup 1.0000x reference)
//
#include <hip/hip_runtime.h>

// LIF recurrence, T=64 fixed by the problem. x: [T, B*N] float32, out: [T, B*N] float32.
// Per column c: v=0; for t: h=(v+x[t][c])*0.5; s=(h>=1); out=s; v=s?0:h.

constexpr int T_STEPS = 64;

__global__ __launch_bounds__(256) void lif_kernel(const float4* __restrict__ x,
                                                  float4* __restrict__ out,
                                                  int cols4) {
    const int idx = blockIdx.x * blockDim.x + threadIdx.x;
    if (idx >= cols4) return;

    const float4* xp = x + idx;
    float4* op = out + idx;

    float4 v = make_float4(0.f, 0.f, 0.f, 0.f);

#pragma unroll 8
    for (int t = 0; t < T_STEPS; ++t) {
        const float4 xt = xp[t * cols4];
        float4 h, s;
        h.x = 0.5f * (v.x + xt.x);
        h.y = 0.5f * (v.y + xt.y);
        h.z = 0.5f * (v.z + xt.z);
        h.w = 0.5f * (v.w + xt.w);
        s.x = (h.x >= 1.0f) ? 1.0f : 0.0f;
        s.y = (h.y >= 1.0f) ? 1.0f : 0.0f;
        s.z = (h.z >= 1.0f) ? 1.0f : 0.0f;
        s.w = (h.w >= 1.0f) ? 1.0f : 0.0f;
        v.x = (h.x >= 1.0f) ? 0.0f : h.x;
        v.y = (h.y >= 1.0f) ? 0.0f : h.y;
        v.z = (h.z >= 1.0f) ? 0.0f : h.z;
        v.w = (h.w >= 1.0f) ? 0.0f : h.w;
        op[t * cols4] = s;
    }
}

extern "C" void kernel_launch(void* const* d_in, const int* in_sizes, int n_in,
                              void* d_out, int out_size, void* d_ws, size_t ws_size,
                              hipStream_t stream) {
    const float* x = (const float*)d_in[0];
    float* out = (float*)d_out;

    const int total = in_sizes[0];            // T * B * N
    const int cols = total / T_STEPS;         // B * N = 524288
    const int cols4 = cols / 4;               // 131072 float4 columns

    const int block = 256;
    const int grid = (cols4 + block - 1) / block;  // 512
    lif_kernel<<<grid, block, 0, stream>>>((const float4*)x, (float4*)out, cols4);
}

// Round 4
// 228.472 us; speedup vs baseline: 1.0136x; 1.0136x over previous
//
#include <hip/hip_runtime.h>

// LIF recurrence, T=64. x: [T, B*N] float32, out: [T, B*N] float32.
// Per column c: v=0; for t: h=(v+x[t][c])*0.5; s=(h>=1); out=s; v=s?0:h.
//
// f32x2 (ext_vector, not HIP_vector_type -- nontemporal builtin requires it)
// per thread -> 262144 threads = 16 waves/CU; non-temporal stores keep x
// LLC-resident and leave the HBM pipe write-dominated.

constexpr int T_STEPS = 64;

typedef float f32x2 __attribute__((ext_vector_type(2)));

__global__ __launch_bounds__(256) void lif_kernel(const f32x2* __restrict__ x,
                                                  f32x2* __restrict__ out,
                                                  int cols2) {
    const int idx = blockIdx.x * blockDim.x + threadIdx.x;
    if (idx >= cols2) return;

    const f32x2* xp = x + idx;
    f32x2* op = out + idx;

    float vx = 0.f, vy = 0.f;

#pragma unroll 16
    for (int t = 0; t < T_STEPS; ++t) {
        const f32x2 xt = xp[t * cols2];
        const float hx = 0.5f * (vx + xt.x);
        const float hy = 0.5f * (vy + xt.y);
        f32x2 s;
        s.x = (hx >= 1.0f) ? 1.0f : 0.0f;
        s.y = (hy >= 1.0f) ? 1.0f : 0.0f;
        vx = (hx >= 1.0f) ? 0.0f : hx;
        vy = (hy >= 1.0f) ? 0.0f : hy;
        __builtin_nontemporal_store(s, &op[t * cols2]);
    }
}

extern "C" void kernel_launch(void* const* d_in, const int* in_sizes, int n_in,
                              void* d_out, int out_size, void* d_ws, size_t ws_size,
                              hipStream_t stream) {
    const float* x = (const float*)d_in[0];
    float* out = (float*)d_out;

    const int total = in_sizes[0];            // T * B * N
    const int cols = total / T_STEPS;         // B * N = 524288
    const int cols2 = cols / 2;               // 262144 f32x2 columns

    const int block = 256;
    const int grid = (cols2 + block - 1) / block;  // 1024
    lif_kernel<<<grid, block, 0, stream>>>((const f32x2*)x, (f32x2*)out, cols2);
}

// Round 5
// 228.426 us; speedup vs baseline: 1.0138x; 1.0002x over previous
//
#include <hip/hip_runtime.h>

// LIF recurrence, T=64. x: [T, B*N] f32, out: [T, B*N] f32.
// Per column c: v=0; for t: h=(v+x[t][c])*0.5; s=(h>=1); out=s; v=s?0:h.
//
// Round-4 diagnosis: latency-bound at ~38 KB in-flight/CU (VGPR_Count=32 capped
// load pipelining). Fix: explicit 2x8 float4 register double-buffer -- all 8
// next-group loads issued before current group's compute+store, ~16 KB
// in-flight per wave. Static indexing only (no scratch).

constexpr int T_STEPS = 64;
constexpr int PF = 8;  // pipeline group depth (timesteps per group)

typedef float f32x4 __attribute__((ext_vector_type(4)));

__global__ __launch_bounds__(256) void lif_kernel(const f32x4* __restrict__ x,
                                                  f32x4* __restrict__ out,
                                                  int cols4) {
    const int idx = blockIdx.x * blockDim.x + threadIdx.x;
    if (idx >= cols4) return;

    const f32x4* xp = x + idx;
    f32x4* op = out + idx;

    f32x4 v = {0.f, 0.f, 0.f, 0.f};
    f32x4 bufA[PF], bufB[PF];

    auto load8 = [&](f32x4 (&dst)[PF], int tbase) {
#pragma unroll
        for (int i = 0; i < PF; ++i)
            dst[i] = xp[(tbase + i) * cols4];
    };

    auto compute8 = [&](f32x4 (&cur)[PF], int tbase) {
#pragma unroll
        for (int i = 0; i < PF; ++i) {
            const f32x4 h = 0.5f * (v + cur[i]);
            f32x4 s;
            s.x = (h.x >= 1.0f) ? 1.0f : 0.0f;
            s.y = (h.y >= 1.0f) ? 1.0f : 0.0f;
            s.z = (h.z >= 1.0f) ? 1.0f : 0.0f;
            s.w = (h.w >= 1.0f) ? 1.0f : 0.0f;
            v.x = (h.x >= 1.0f) ? 0.0f : h.x;
            v.y = (h.y >= 1.0f) ? 0.0f : h.y;
            v.z = (h.z >= 1.0f) ? 0.0f : h.z;
            v.w = (h.w >= 1.0f) ? 0.0f : h.w;
            __builtin_nontemporal_store(s, &op[(tbase + i) * cols4]);
        }
    };

    // Software pipeline: 2 groups of loads always in flight ahead of compute.
    load8(bufA, 0);
    load8(bufB, 8);
    compute8(bufA, 0);   load8(bufA, 16);
    compute8(bufB, 8);   load8(bufB, 24);
    compute8(bufA, 16);  load8(bufA, 32);
    compute8(bufB, 24);  load8(bufB, 40);
    compute8(bufA, 32);  load8(bufA, 48);
    compute8(bufB, 40);  load8(bufB, 56);
    compute8(bufA, 48);
    compute8(bufB, 56);
}

extern "C" void kernel_launch(void* const* d_in, const int* in_sizes, int n_in,
                              void* d_out, int out_size, void* d_ws, size_t ws_size,
                              hipStream_t stream) {
    const float* x = (const float*)d_in[0];
    float* out = (float*)d_out;

    const int total = in_sizes[0];            // T * B * N
    const int cols = total / T_STEPS;         // B * N = 524288
    const int cols4 = cols / 4;               // 131072 f32x4 columns

    const int block = 256;
    const int grid = (cols4 + block - 1) / block;  // 512
    lif_kernel<<<grid, block, 0, stream>>>((const f32x4*)x, (f32x4*)out, cols4);
}